// Round 1
// baseline (1415.279 us; speedup 1.0000x reference)
//
#include <hip/hip_runtime.h>

#define NN 50000
#define HID 256

// ---------------- CSR build ----------------
__global__ void k_count(const int* __restrict__ dst, int E, int* __restrict__ deg) {
    int i = blockIdx.x * blockDim.x + threadIdx.x;
    if (i < E) atomicAdd(&deg[dst[i]], 1);
}

// exclusive scan, 1024 elems per block (256 thr x 4)
__global__ void k_scan1(const int* __restrict__ deg, int n,
                        int* __restrict__ out, int* __restrict__ bsum) {
    __shared__ int s[256];
    int t = threadIdx.x;
    int base = blockIdx.x * 1024;
    int v[4]; int sum = 0;
#pragma unroll
    for (int r = 0; r < 4; r++) {
        int idx = base + t * 4 + r;
        v[r] = (idx < n) ? deg[idx] : 0;
        sum += v[r];
    }
    s[t] = sum; __syncthreads();
    for (int off = 1; off < 256; off <<= 1) {
        int x = (t >= off) ? s[t - off] : 0;
        __syncthreads();
        s[t] += x;
        __syncthreads();
    }
    int excl = s[t] - sum;
    if (t == 255) bsum[blockIdx.x] = s[255];
    int run = excl;
#pragma unroll
    for (int r = 0; r < 4; r++) {
        int idx = base + t * 4 + r;
        if (idx < n) out[idx] = run;
        run += v[r];
    }
}

__global__ void k_scan2(int* __restrict__ bsum, int nb) {
    __shared__ int s[64];
    int t = threadIdx.x;
    int orig = (t < nb) ? bsum[t] : 0;
    s[t] = orig; __syncthreads();
    for (int off = 1; off < 64; off <<= 1) {
        int x = (t >= off) ? s[t - off] : 0;
        __syncthreads();
        s[t] += x;
        __syncthreads();
    }
    if (t < nb) bsum[t] = s[t] - orig;
}

__global__ void k_scan3(int* __restrict__ rowptr, const int* __restrict__ bsum,
                        int n, int E) {
    int i = blockIdx.x * blockDim.x + threadIdx.x;
    if (i < n) rowptr[i] += bsum[i >> 10];
    if (i == 0) rowptr[n] = E;
}

__global__ void k_fill(const int* __restrict__ dst, const int* __restrict__ src, int E,
                       const int* __restrict__ rowptr, int* __restrict__ fpos,
                       int* __restrict__ col) {
    int e = blockIdx.x * blockDim.x + threadIdx.x;
    if (e < E) {
        int d = dst[e];
        int p = atomicAdd(&fpos[d], 1);
        col[rowptr[d] + p] = src[e];
    }
}

// ---------------- aggregation (segment mean via CSR gather) ----------------
template <int D>
__global__ void k_agg(const float* __restrict__ H, const int* __restrict__ rowptr,
                      const int* __restrict__ col, float* __restrict__ agg) {
    __shared__ int sc[64];
    int node = blockIdx.x;
    int f = threadIdx.x;           // D threads
    int beg = rowptr[node], end = rowptr[node + 1];
    float sum = 0.f;
    for (int c = beg; c < end; c += 64) {
        int nchunk = min(64, end - c);
        __syncthreads();
        if (f < nchunk) sc[f] = col[c + f];
        __syncthreads();
        for (int j = 0; j < nchunk; j++)
            sum += H[(size_t)sc[j] * D + f];
    }
    float dg = (float)(end - beg);
    agg[(size_t)node * D + f] = sum / fmaxf(dg, 1.f);
}

// ---------------- fused GEMM: out = epi(agg@Wl + bl + h@Wr) ----------------
// block: (64,4)=256 thr; tile: 16 rows x 64 cols; each thread 4 rows x 1 col
template <int K, bool RELU, bool FINAL>
__global__ __launch_bounds__(256) void k_gemm(
    const float* __restrict__ A,   // agg [M][K]
    const float* __restrict__ H,   // h   [M][K]
    const float* __restrict__ Wl,  // [K][256]
    const float* __restrict__ Wr,  // [K][256]
    const float* __restrict__ bias,// [256]
    const float* __restrict__ h1,  // FINAL only
    const float* __restrict__ h2,  // FINAL only
    float* __restrict__ out, int M)
{
    __shared__ float sA[16][K];
    __shared__ float sH[16][K];
    int tx = threadIdx.x;                 // col in tile
    int ty = threadIdx.y;
    int tid = ty * 64 + tx;
    int row0 = blockIdx.y * 16;
    int col = blockIdx.x * 64 + tx;

    const float4* A4 = (const float4*)(A + (size_t)row0 * K);
    const float4* H4 = (const float4*)(H + (size_t)row0 * K);
    float4* sA4 = (float4*)&sA[0][0];
    float4* sH4 = (float4*)&sH[0][0];
    const int ELEMS = 16 * K / 4;
#pragma unroll
    for (int i = tid; i < ELEMS; i += 256) { sA4[i] = A4[i]; sH4[i] = H4[i]; }
    __syncthreads();

    float acc[4] = {0.f, 0.f, 0.f, 0.f};
    for (int k = 0; k < K; k++) {
        float wl = Wl[k * 256 + col];
        float wr = Wr[k * 256 + col];
#pragma unroll
        for (int r = 0; r < 4; r++) {
            acc[r] += sA[ty * 4 + r][k] * wl + sH[ty * 4 + r][k] * wr;
        }
    }
    float bb = bias[col];
#pragma unroll
    for (int r = 0; r < 4; r++) {
        int row = row0 + ty * 4 + r;
        size_t o = (size_t)row * 256 + col;
        float z = acc[r] + bb;
        if (RELU) z = fmaxf(z, 0.f);
        if (FINAL) z = fmaxf(z, fmaxf(h1[o], h2[o]));
        out[o] = z;
    }
}

extern "C" void kernel_launch(void* const* d_in, const int* in_sizes, int n_in,
                              void* d_out, int out_size, void* d_ws, size_t ws_size,
                              hipStream_t stream) {
    const float* x   = (const float*)d_in[0];
    const int*   ei  = (const int*)d_in[1];
    const float* Wl0 = (const float*)d_in[2];
    const float* bl0 = (const float*)d_in[3];
    const float* Wr0 = (const float*)d_in[4];
    const float* Wl1 = (const float*)d_in[5];
    const float* bl1 = (const float*)d_in[6];
    const float* Wr1 = (const float*)d_in[7];
    const float* Wl2 = (const float*)d_in[8];
    const float* bl2 = (const float*)d_in[9];
    const float* Wr2 = (const float*)d_in[10];
    float* out = (float*)d_out;

    const int N = NN;
    const int E = in_sizes[1] / 2;
    const int* dst = ei;          // edge_index[0]
    const int* src = ei + E;      // edge_index[1]

    // workspace carve (256B aligned)
    char* w = (char*)d_ws;
    size_t off = 0;
    auto carve = [&](size_t bytes) {
        char* p = w + off;
        off += (bytes + 255) & ~(size_t)255;
        return p;
    };
    int*   deg    = (int*)  carve((size_t)N * 4);
    int*   rowptr = (int*)  carve((size_t)(N + 1) * 4);
    int*   fpos   = (int*)  carve((size_t)N * 4);
    int*   bsum   = (int*)  carve(64 * 4);
    int*   colb   = (int*)  carve((size_t)E * 4);
    float* agg    = (float*)carve((size_t)N * HID * 4);
    float* h1     = (float*)carve((size_t)N * HID * 4);
    float* h2     = (float*)carve((size_t)N * HID * 4);
    (void)ws_size; (void)n_in; (void)out_size;

    hipMemsetAsync(deg, 0, (size_t)N * 4, stream);
    hipMemsetAsync(fpos, 0, (size_t)N * 4, stream);

    k_count<<<(E + 255) / 256, 256, 0, stream>>>(dst, E, deg);
    int nb = (N + 1023) / 1024;                       // 49
    k_scan1<<<nb, 256, 0, stream>>>(deg, N, rowptr, bsum);
    k_scan2<<<1, 64, 0, stream>>>(bsum, nb);
    k_scan3<<<(N + 255) / 256, 256, 0, stream>>>(rowptr, bsum, N, E);
    k_fill<<<(E + 255) / 256, 256, 0, stream>>>(dst, src, E, rowptr, fpos, colb);

    dim3 gblk(64, 4);

    // layer 0: K=128, relu
    k_agg<128><<<N, 128, 0, stream>>>(x, rowptr, colb, agg);
    k_gemm<128, true, false><<<dim3(4, N / 16), gblk, 0, stream>>>(
        agg, x, Wl0, Wr0, bl0, nullptr, nullptr, h1, N);

    // layer 1: K=256, relu
    k_agg<256><<<N, 256, 0, stream>>>(h1, rowptr, colb, agg);
    k_gemm<256, true, false><<<dim3(4, N / 16), gblk, 0, stream>>>(
        agg, h1, Wl1, Wr1, bl1, nullptr, nullptr, h2, N);

    // layer 2: K=256, JK-max epilogue
    k_agg<256><<<N, 256, 0, stream>>>(h2, rowptr, colb, agg);
    k_gemm<256, false, true><<<dim3(4, N / 16), gblk, 0, stream>>>(
        agg, h2, Wl2, Wr2, bl2, h1, h2, out, N);
}

// Round 2
// 464.755 us; speedup vs baseline: 3.0452x; 3.0452x over previous
//
#include <hip/hip_runtime.h>

#define NN 50000
#define MPAD 50048   // 782 * 64, padded row count for 64-row GEMM tiles

typedef unsigned short u16;
typedef unsigned int u32;
typedef short s16x8 __attribute__((ext_vector_type(8)));   // 8 bf16 (4 VGPRs)
typedef float f32x4 __attribute__((ext_vector_type(4)));

__device__ inline u16 f2bf(float f) {
    u32 u = __float_as_uint(f);
    u32 r = (u + 0x7FFF + ((u >> 16) & 1)) >> 16;   // RNE
    return (u16)r;
}
__device__ inline float bf2f(u16 s) { return __uint_as_float(((u32)s) << 16); }

template <typename T>
__device__ inline const __attribute__((address_space(1))) T* as_g(const T* p) {
    return (const __attribute__((address_space(1))) T*)p;
}
template <typename T>
__device__ inline __attribute__((address_space(3))) T* as_l(T* p) {
    return (__attribute__((address_space(3))) T*)p;
}

// ---------------- CSR build ----------------
__global__ void k_count(const int* __restrict__ dst, int E, int* __restrict__ deg) {
    int i = blockIdx.x * blockDim.x + threadIdx.x;
    if (i < E) atomicAdd(&deg[dst[i]], 1);
}

__global__ void k_scan1(const int* __restrict__ deg, int n,
                        int* __restrict__ out, int* __restrict__ bsum) {
    __shared__ int s[256];
    int t = threadIdx.x;
    int base = blockIdx.x * 1024;
    int v[4]; int sum = 0;
#pragma unroll
    for (int r = 0; r < 4; r++) {
        int idx = base + t * 4 + r;
        v[r] = (idx < n) ? deg[idx] : 0;
        sum += v[r];
    }
    s[t] = sum; __syncthreads();
    for (int off = 1; off < 256; off <<= 1) {
        int x = (t >= off) ? s[t - off] : 0;
        __syncthreads();
        s[t] += x;
        __syncthreads();
    }
    int excl = s[t] - sum;
    if (t == 255) bsum[blockIdx.x] = s[255];
    int run = excl;
#pragma unroll
    for (int r = 0; r < 4; r++) {
        int idx = base + t * 4 + r;
        if (idx < n) out[idx] = run;
        run += v[r];
    }
}

__global__ void k_scan2(int* __restrict__ bsum, int nb) {
    __shared__ int s[64];
    int t = threadIdx.x;
    int orig = (t < nb) ? bsum[t] : 0;
    s[t] = orig; __syncthreads();
    for (int off = 1; off < 64; off <<= 1) {
        int x = (t >= off) ? s[t - off] : 0;
        __syncthreads();
        s[t] += x;
        __syncthreads();
    }
    if (t < nb) bsum[t] = s[t] - orig;
}

__global__ void k_scan3(int* __restrict__ rowptr, const int* __restrict__ bsum,
                        int n, int E) {
    int i = blockIdx.x * blockDim.x + threadIdx.x;
    if (i < n) rowptr[i] += bsum[i >> 10];
    if (i == 0) rowptr[n] = E;
}

__global__ void k_fill(const int* __restrict__ dst, const int* __restrict__ src, int E,
                       const int* __restrict__ rowptr, int* __restrict__ fpos,
                       int* __restrict__ col) {
    int e = blockIdx.x * blockDim.x + threadIdx.x;
    if (e < E) {
        int d = dst[e];
        int p = atomicAdd(&fpos[d], 1);
        col[rowptr[d] + p] = src[e];
    }
}

// ---------------- casts ----------------
// x (f32 [NN][128]) -> xb (bf16 [MPAD][128]), pad rows zero. 4 floats/thread.
__global__ void k_castx(const float* __restrict__ x, u16* __restrict__ xb) {
    int i = blockIdx.x * 256 + threadIdx.x;
    int idx = i * 4;
    u32 lo = 0, hi = 0;
    if (idx < NN * 128) {
        float4 v = *reinterpret_cast<const float4*>(x + idx);
        lo = (u32)f2bf(v.x) | ((u32)f2bf(v.y) << 16);
        hi = (u32)f2bf(v.z) | ((u32)f2bf(v.w) << 16);
    }
    uint2 o; o.x = lo; o.y = hi;
    *reinterpret_cast<uint2*>(xb + idx) = o;
}

// Wt[n][k] bf16, k in [0,2K): k<K -> Wl[k][n], else Wr[k-K][n]
__global__ void k_wcat(const float* __restrict__ Wl, const float* __restrict__ Wr,
                       int K, u16* __restrict__ Wt) {
    int idx = blockIdx.x * 256 + threadIdx.x;
    int KC = 2 * K;
    if (idx >= 256 * KC) return;
    int n = idx / KC;
    int k = idx - n * KC;
    float v = (k < K) ? Wl[(size_t)k * 256 + n] : Wr[(size_t)(k - K) * 256 + n];
    Wt[idx] = f2bf(v);
}

// ---------------- aggregation (segment mean, bf16 in/out) ----------------
// one wave per node; lane covers D/64 features
template <int D>
__global__ __launch_bounds__(256) void k_aggb(
    const u16* __restrict__ H, const int* __restrict__ rowptr,
    const int* __restrict__ col, u16* __restrict__ out) {
    constexpr int PER = D / 64;    // 2 or 4
    int wv = threadIdx.x >> 6, l = threadIdx.x & 63;
    int node = blockIdx.x * 4 + wv;
    if (node >= MPAD) return;
    size_t obase = (size_t)node * D + l * PER;
    if (node >= NN) {
        if (PER == 2) *reinterpret_cast<u32*>(out + obase) = 0;
        else { uint2 z; z.x = 0; z.y = 0; *reinterpret_cast<uint2*>(out + obase) = z; }
        return;
    }
    int beg = rowptr[node], end = rowptr[node + 1];
    float acc[PER];
#pragma unroll
    for (int j = 0; j < PER; j++) acc[j] = 0.f;
    for (int c = beg; c < end; ++c) {
        int nb = col[c];   // wave-uniform -> scalar load
        const u16* hp = H + (size_t)nb * D + l * PER;
        if (PER == 2) {
            u32 v = *reinterpret_cast<const u32*>(hp);
            acc[0] += bf2f((u16)(v & 0xFFFF));
            acc[1] += bf2f((u16)(v >> 16));
        } else {
            uint2 v = *reinterpret_cast<const uint2*>(hp);
            acc[0] += bf2f((u16)(v.x & 0xFFFF));
            acc[1] += bf2f((u16)(v.x >> 16));
            acc[2] += bf2f((u16)(v.y & 0xFFFF));
            acc[3] += bf2f((u16)(v.y >> 16));
        }
    }
    float inv = 1.f / fmaxf((float)(end - beg), 1.f);
    if (PER == 2) {
        u32 o = (u32)f2bf(acc[0] * inv) | ((u32)f2bf(acc[1] * inv) << 16);
        *reinterpret_cast<u32*>(out + obase) = o;
    } else {
        uint2 o;
        o.x = (u32)f2bf(acc[0] * inv) | ((u32)f2bf(acc[1] * inv) << 16);
        o.y = (u32)f2bf(acc[2] * inv) | ((u32)f2bf(acc[3] * inv) << 16);
        *reinterpret_cast<uint2*>(out + obase) = o;
    }
}

// ---------------- MFMA GEMM: out = epi([agg,h] @ Wt^T + b) ----------------
// BM=64, BN=256 (full width), BK=64. 256 thr = 4 waves; wave w owns cols w*64..w*64+63.
// A tile: sA[64][64] bf16 (8KB), B tile: sB[256][64] bf16 (32KB), both XOR-swizzled
// on 16B chunks: chunk' = chunk ^ (row&7); staged via global_load_lds (linear dest,
// inverse-swizzled per-lane source), read with same XOR -> conflict-free ds_read_b128.
template <int K, int MODE>   // MODE 0: relu -> bf16 store; MODE 1: JK-max -> f32 out
__global__ __launch_bounds__(256) void k_mgemm(
    const u16* __restrict__ Aagg, const u16* __restrict__ Ah,
    const u16* __restrict__ Wt, const float* __restrict__ bias,
    const u16* __restrict__ h1b, const u16* __restrict__ h2b,
    u16* __restrict__ outb, float* __restrict__ outf) {
    constexpr int KC = 2 * K;
    constexpr int NSTEP = KC / 64;
    __shared__ u16 sA[64 * 64];
    __shared__ u16 sB[256 * 64];
    int tid = threadIdx.x;
    int w = tid >> 6, l = tid & 63;
    int row0 = blockIdx.x * 64;
    int lr = l & 15, lk = l >> 4;

    f32x4 acc[4][4];
#pragma unroll
    for (int m = 0; m < 4; m++)
#pragma unroll
        for (int n = 0; n < 4; n++) acc[m][n] = (f32x4){0.f, 0.f, 0.f, 0.f};

    for (int st = 0; st < NSTEP; ++st) {
        int kk = st * 64;
        const u16* Ab = (kk < K) ? Aagg : Ah;
        int koff = (kk < K) ? kk : kk - K;
        // stage A: 64 rows x 8 chunks = 512 chunks, 2 rounds of 256
#pragma unroll
        for (int s = 0; s < 2; ++s) {
            int p = s * 256 + tid;
            int r = p >> 3, c = p & 7;
            int g = c ^ (r & 7);
            const u16* ga = Ab + (size_t)(row0 + r) * K + koff + g * 8;
            u16* lb = sA + (size_t)(s * 256 + (tid & ~63)) * 8;
            __builtin_amdgcn_global_load_lds(as_g(ga), as_l(lb), 16, 0, 0);
        }
        // stage B: 256 rows x 8 chunks = 2048 chunks, 8 rounds
#pragma unroll
        for (int s = 0; s < 8; ++s) {
            int p = s * 256 + tid;
            int r = p >> 3, c = p & 7;
            int g = c ^ (r & 7);
            const u16* ga = Wt + (size_t)r * KC + kk + g * 8;
            u16* lb = sB + (size_t)(s * 256 + (tid & ~63)) * 8;
            __builtin_amdgcn_global_load_lds(as_g(ga), as_l(lb), 16, 0, 0);
        }
        __syncthreads();
#pragma unroll
        for (int kk2 = 0; kk2 < 2; ++kk2) {
            s16x8 av[4], bv[4];
#pragma unroll
            for (int m = 0; m < 4; ++m) {
                int r = m * 16 + lr;
                int cidx = kk2 * 4 + lk;
                int off = r * 128 + ((cidx ^ (lr & 7)) << 4);
                av[m] = *reinterpret_cast<const s16x8*>(
                    reinterpret_cast<const char*>(sA) + off);
            }
#pragma unroll
            for (int n = 0; n < 4; ++n) {
                int r = w * 64 + n * 16 + lr;
                int cidx = kk2 * 4 + lk;
                int off = r * 128 + ((cidx ^ (lr & 7)) << 4);
                bv[n] = *reinterpret_cast<const s16x8*>(
                    reinterpret_cast<const char*>(sB) + off);
            }
#pragma unroll
            for (int m = 0; m < 4; ++m)
#pragma unroll
                for (int n = 0; n < 4; ++n)
                    acc[m][n] = __builtin_amdgcn_mfma_f32_16x16x32_bf16(
                        av[m], bv[n], acc[m][n], 0, 0, 0);
        }
        __syncthreads();
    }

    // epilogue: D[(l>>4)*4+i][l&15] per 16x16 frag
    float bb[4];
#pragma unroll
    for (int n = 0; n < 4; ++n) bb[n] = bias[w * 64 + n * 16 + lr];
#pragma unroll
    for (int m = 0; m < 4; ++m) {
#pragma unroll
        for (int n = 0; n < 4; ++n) {
            int col = w * 64 + n * 16 + lr;
#pragma unroll
            for (int i = 0; i < 4; ++i) {
                int row = row0 + m * 16 + lk * 4 + i;
                size_t o = (size_t)row * 256 + col;
                float z = acc[m][n][i] + bb[n];
                if (MODE == 0) {
                    z = fmaxf(z, 0.f);
                    outb[o] = f2bf(z);
                } else {
                    if (row < NN) {
                        z = fmaxf(z, fmaxf(bf2f(h1b[o]), bf2f(h2b[o])));
                        outf[o] = z;
                    }
                }
            }
        }
    }
}

extern "C" void kernel_launch(void* const* d_in, const int* in_sizes, int n_in,
                              void* d_out, int out_size, void* d_ws, size_t ws_size,
                              hipStream_t stream) {
    const float* x   = (const float*)d_in[0];
    const int*   ei  = (const int*)d_in[1];
    const float* Wl0 = (const float*)d_in[2];
    const float* bl0 = (const float*)d_in[3];
    const float* Wr0 = (const float*)d_in[4];
    const float* Wl1 = (const float*)d_in[5];
    const float* bl1 = (const float*)d_in[6];
    const float* Wr1 = (const float*)d_in[7];
    const float* Wl2 = (const float*)d_in[8];
    const float* bl2 = (const float*)d_in[9];
    const float* Wr2 = (const float*)d_in[10];
    float* out = (float*)d_out;

    const int N = NN;
    const int E = in_sizes[1] / 2;
    const int* dst = ei;          // edge_index[0]
    const int* src = ei + E;      // edge_index[1]

    char* wsp = (char*)d_ws;
    size_t off = 0;
    auto carve = [&](size_t bytes) {
        char* p = wsp + off;
        off += (bytes + 255) & ~(size_t)255;
        return p;
    };
    int* deg    = (int*)carve((size_t)N * 4);
    int* rowptr = (int*)carve((size_t)(N + 1) * 4);
    int* fpos   = (int*)carve((size_t)N * 4);
    int* bsum   = (int*)carve(64 * 4);
    int* colb   = (int*)carve((size_t)E * 4);
    u16* xb     = (u16*)carve((size_t)MPAD * 128 * 2);
    u16* aggb   = (u16*)carve((size_t)MPAD * 256 * 2);
    u16* h1b    = (u16*)carve((size_t)MPAD * 256 * 2);
    u16* h2b    = (u16*)carve((size_t)MPAD * 256 * 2);
    u16* Wt0    = (u16*)carve((size_t)256 * 256 * 2);
    u16* Wt1    = (u16*)carve((size_t)256 * 512 * 2);
    u16* Wt2    = (u16*)carve((size_t)256 * 512 * 2);
    (void)ws_size; (void)n_in; (void)out_size;

    hipMemsetAsync(deg, 0, (size_t)N * 4, stream);
    hipMemsetAsync(fpos, 0, (size_t)N * 4, stream);

    k_count<<<(E + 255) / 256, 256, 0, stream>>>(dst, E, deg);
    int nb = (N + 1023) / 1024;   // 49
    k_scan1<<<nb, 256, 0, stream>>>(deg, N, rowptr, bsum);
    k_scan2<<<1, 64, 0, stream>>>(bsum, nb);
    k_scan3<<<(N + 255) / 256, 256, 0, stream>>>(rowptr, bsum, N, E);
    k_fill<<<(E + 255) / 256, 256, 0, stream>>>(dst, src, E, rowptr, fpos, colb);

    // casts
    k_castx<<<(MPAD * 128 / 4) / 256, 256, 0, stream>>>(x, xb);
    k_wcat<<<256, 256, 0, stream>>>(Wl0, Wr0, 128, Wt0);
    k_wcat<<<512, 256, 0, stream>>>(Wl1, Wr1, 256, Wt1);
    k_wcat<<<512, 256, 0, stream>>>(Wl2, Wr2, 256, Wt2);

    const int GB = MPAD / 64;   // 782 blocks
    const int GA = MPAD / 4;    // 12512 blocks

    // layer 0: K=128
    k_aggb<128><<<GA, 256, 0, stream>>>(xb, rowptr, colb, aggb);
    k_mgemm<128, 0><<<GB, 256, 0, stream>>>(aggb, xb, Wt0, bl0, nullptr, nullptr,
                                            h1b, nullptr);
    // layer 1: K=256
    k_aggb<256><<<GA, 256, 0, stream>>>(h1b, rowptr, colb, aggb);
    k_mgemm<256, 0><<<GB, 256, 0, stream>>>(aggb, h1b, Wt1, bl1, nullptr, nullptr,
                                            h2b, nullptr);
    // layer 2: K=256, JK-max epilogue
    k_aggb<256><<<GA, 256, 0, stream>>>(h2b, rowptr, colb, aggb);
    k_mgemm<256, 1><<<GB, 256, 0, stream>>>(aggb, h2b, Wt2, bl2, h1b, h2b,
                                            nullptr, out);
}

// Round 3
// 355.691 us; speedup vs baseline: 3.9790x; 1.3066x over previous
//
#include <hip/hip_runtime.h>

#define NN 50000
#define MPAD 50048   // 782 * 64, padded row count for 64-row GEMM tiles

typedef unsigned short u16;
typedef unsigned int u32;
typedef short s16x8 __attribute__((ext_vector_type(8)));   // 8 bf16 (4 VGPRs)
typedef float f32x4 __attribute__((ext_vector_type(4)));

__device__ inline u16 f2bf(float f) {
    u32 u = __float_as_uint(f);
    u32 r = (u + 0x7FFF + ((u >> 16) & 1)) >> 16;   // RNE
    return (u16)r;
}
__device__ inline float bf2f(u16 s) { return __uint_as_float(((u32)s) << 16); }

template <typename T>
__device__ inline const __attribute__((address_space(1))) T* as_g(const T* p) {
    return (const __attribute__((address_space(1))) T*)p;
}
template <typename T>
__device__ inline __attribute__((address_space(3))) T* as_l(T* p) {
    return (__attribute__((address_space(3))) T*)p;
}

// ---------------- CSR build ----------------
__global__ void k_count(const int* __restrict__ dst, int E, int* __restrict__ deg) {
    int i = blockIdx.x * blockDim.x + threadIdx.x;
    if (i < E) atomicAdd(&deg[dst[i]], 1);
}

__global__ void k_scan1(const int* __restrict__ deg, int n,
                        int* __restrict__ out, int* __restrict__ bsum) {
    __shared__ int s[256];
    int t = threadIdx.x;
    int base = blockIdx.x * 1024;
    int v[4]; int sum = 0;
#pragma unroll
    for (int r = 0; r < 4; r++) {
        int idx = base + t * 4 + r;
        v[r] = (idx < n) ? deg[idx] : 0;
        sum += v[r];
    }
    s[t] = sum; __syncthreads();
    for (int off = 1; off < 256; off <<= 1) {
        int x = (t >= off) ? s[t - off] : 0;
        __syncthreads();
        s[t] += x;
        __syncthreads();
    }
    int excl = s[t] - sum;
    if (t == 255) bsum[blockIdx.x] = s[255];
    int run = excl;
#pragma unroll
    for (int r = 0; r < 4; r++) {
        int idx = base + t * 4 + r;
        if (idx < n) out[idx] = run;
        run += v[r];
    }
}

__global__ void k_scan2(int* __restrict__ bsum, int nb) {
    __shared__ int s[64];
    int t = threadIdx.x;
    int orig = (t < nb) ? bsum[t] : 0;
    s[t] = orig; __syncthreads();
    for (int off = 1; off < 64; off <<= 1) {
        int x = (t >= off) ? s[t - off] : 0;
        __syncthreads();
        s[t] += x;
        __syncthreads();
    }
    if (t < nb) bsum[t] = s[t] - orig;
}

__global__ void k_scan3(int* __restrict__ rowptr, const int* __restrict__ bsum,
                        int n, int E) {
    int i = blockIdx.x * blockDim.x + threadIdx.x;
    if (i < n) rowptr[i] += bsum[i >> 10];
    if (i == 0) rowptr[n] = E;
}

__global__ void k_fill(const int* __restrict__ dst, const int* __restrict__ src, int E,
                       const int* __restrict__ rowptr, int* __restrict__ fpos,
                       int* __restrict__ col) {
    int e = blockIdx.x * blockDim.x + threadIdx.x;
    if (e < E) {
        int d = dst[e];
        int p = atomicAdd(&fpos[d], 1);
        col[rowptr[d] + p] = src[e];
    }
}

// ---------------- casts ----------------
__global__ void k_castx(const float* __restrict__ x, u16* __restrict__ xb) {
    int i = blockIdx.x * 256 + threadIdx.x;
    int idx = i * 4;
    u32 lo = 0, hi = 0;
    if (idx < NN * 128) {
        float4 v = *reinterpret_cast<const float4*>(x + idx);
        lo = (u32)f2bf(v.x) | ((u32)f2bf(v.y) << 16);
        hi = (u32)f2bf(v.z) | ((u32)f2bf(v.w) << 16);
    }
    uint2 o; o.x = lo; o.y = hi;
    *reinterpret_cast<uint2*>(xb + idx) = o;
}

__global__ void k_wcat(const float* __restrict__ Wl, const float* __restrict__ Wr,
                       int K, u16* __restrict__ Wt) {
    int idx = blockIdx.x * 256 + threadIdx.x;
    int KC = 2 * K;
    if (idx >= 256 * KC) return;
    int n = idx / KC;
    int k = idx - n * KC;
    float v = (k < K) ? Wl[(size_t)k * 256 + n] : Wr[(size_t)(k - K) * 256 + n];
    Wt[idx] = f2bf(v);
}

// ---------------- aggregation (segment mean, bf16 in/out) ----------------
// one wave per node; lane covers D/64 features. Neighbor loop unrolled x4:
// four independent row-gathers in flight per wave (MLP for latency hiding).
template <int D>
__global__ __launch_bounds__(256) void k_aggb(
    const u16* __restrict__ H, const int* __restrict__ rowptr,
    const int* __restrict__ col, u16* __restrict__ out) {
    constexpr int PER = D / 64;    // 2 or 4
    int wv = threadIdx.x >> 6, l = threadIdx.x & 63;
    int node = blockIdx.x * 4 + wv;
    if (node >= MPAD) return;
    size_t obase = (size_t)node * D + l * PER;
    if (node >= NN) {
        if (PER == 2) *reinterpret_cast<u32*>(out + obase) = 0;
        else { uint2 z; z.x = 0; z.y = 0; *reinterpret_cast<uint2*>(out + obase) = z; }
        return;
    }
    int beg = rowptr[node], end = rowptr[node + 1];
    float acc[PER];
#pragma unroll
    for (int j = 0; j < PER; j++) acc[j] = 0.f;

    int c = beg;
    if (PER == 2) {
        const int fo = l * 2;
        for (; c + 4 <= end; c += 4) {
            int n0 = col[c + 0], n1 = col[c + 1], n2 = col[c + 2], n3 = col[c + 3];
            u32 v0 = *reinterpret_cast<const u32*>(H + (size_t)n0 * D + fo);
            u32 v1 = *reinterpret_cast<const u32*>(H + (size_t)n1 * D + fo);
            u32 v2 = *reinterpret_cast<const u32*>(H + (size_t)n2 * D + fo);
            u32 v3 = *reinterpret_cast<const u32*>(H + (size_t)n3 * D + fo);
            acc[0] += bf2f((u16)(v0 & 0xFFFF)) + bf2f((u16)(v1 & 0xFFFF)) +
                      bf2f((u16)(v2 & 0xFFFF)) + bf2f((u16)(v3 & 0xFFFF));
            acc[1] += bf2f((u16)(v0 >> 16)) + bf2f((u16)(v1 >> 16)) +
                      bf2f((u16)(v2 >> 16)) + bf2f((u16)(v3 >> 16));
        }
        for (; c < end; ++c) {
            u32 v = *reinterpret_cast<const u32*>(H + (size_t)col[c] * D + fo);
            acc[0] += bf2f((u16)(v & 0xFFFF));
            acc[1] += bf2f((u16)(v >> 16));
        }
    } else {
        const int fo = l * 4;
        for (; c + 4 <= end; c += 4) {
            int n0 = col[c + 0], n1 = col[c + 1], n2 = col[c + 2], n3 = col[c + 3];
            uint2 v0 = *reinterpret_cast<const uint2*>(H + (size_t)n0 * D + fo);
            uint2 v1 = *reinterpret_cast<const uint2*>(H + (size_t)n1 * D + fo);
            uint2 v2 = *reinterpret_cast<const uint2*>(H + (size_t)n2 * D + fo);
            uint2 v3 = *reinterpret_cast<const uint2*>(H + (size_t)n3 * D + fo);
            acc[0] += bf2f((u16)(v0.x & 0xFFFF)) + bf2f((u16)(v1.x & 0xFFFF)) +
                      bf2f((u16)(v2.x & 0xFFFF)) + bf2f((u16)(v3.x & 0xFFFF));
            acc[1] += bf2f((u16)(v0.x >> 16)) + bf2f((u16)(v1.x >> 16)) +
                      bf2f((u16)(v2.x >> 16)) + bf2f((u16)(v3.x >> 16));
            acc[2] += bf2f((u16)(v0.y & 0xFFFF)) + bf2f((u16)(v1.y & 0xFFFF)) +
                      bf2f((u16)(v2.y & 0xFFFF)) + bf2f((u16)(v3.y & 0xFFFF));
            acc[3] += bf2f((u16)(v0.y >> 16)) + bf2f((u16)(v1.y >> 16)) +
                      bf2f((u16)(v2.y >> 16)) + bf2f((u16)(v3.y >> 16));
        }
        for (; c < end; ++c) {
            uint2 v = *reinterpret_cast<const uint2*>(H + (size_t)col[c] * D + fo);
            acc[0] += bf2f((u16)(v.x & 0xFFFF));
            acc[1] += bf2f((u16)(v.x >> 16));
            acc[2] += bf2f((u16)(v.y & 0xFFFF));
            acc[3] += bf2f((u16)(v.y >> 16));
        }
    }
    float inv = 1.f / fmaxf((float)(end - beg), 1.f);
    if (PER == 2) {
        u32 o = (u32)f2bf(acc[0] * inv) | ((u32)f2bf(acc[1] * inv) << 16);
        *reinterpret_cast<u32*>(out + obase) = o;
    } else {
        uint2 o;
        o.x = (u32)f2bf(acc[0] * inv) | ((u32)f2bf(acc[1] * inv) << 16);
        o.y = (u32)f2bf(acc[2] * inv) | ((u32)f2bf(acc[3] * inv) << 16);
        *reinterpret_cast<uint2*>(out + obase) = o;
    }
}

// ---------------- MFMA GEMM: out = epi([agg,h] @ Wt^T + b) ----------------
template <int K, int MODE>   // MODE 0: relu -> bf16 store; MODE 1: JK-max -> f32 out
__global__ __launch_bounds__(256) void k_mgemm(
    const u16* __restrict__ Aagg, const u16* __restrict__ Ah,
    const u16* __restrict__ Wt, const float* __restrict__ bias,
    const u16* __restrict__ h1b, const u16* __restrict__ h2b,
    u16* __restrict__ outb, float* __restrict__ outf) {
    constexpr int KC = 2 * K;
    constexpr int NSTEP = KC / 64;
    __shared__ u16 sA[64 * 64];
    __shared__ u16 sB[256 * 64];
    int tid = threadIdx.x;
    int w = tid >> 6, l = tid & 63;
    int row0 = blockIdx.x * 64;
    int lr = l & 15, lk = l >> 4;

    f32x4 acc[4][4];
#pragma unroll
    for (int m = 0; m < 4; m++)
#pragma unroll
        for (int n = 0; n < 4; n++) acc[m][n] = (f32x4){0.f, 0.f, 0.f, 0.f};

    for (int st = 0; st < NSTEP; ++st) {
        int kk = st * 64;
        const u16* Ab = (kk < K) ? Aagg : Ah;
        int koff = (kk < K) ? kk : kk - K;
#pragma unroll
        for (int s = 0; s < 2; ++s) {
            int p = s * 256 + tid;
            int r = p >> 3, c = p & 7;
            int g = c ^ (r & 7);
            const u16* ga = Ab + (size_t)(row0 + r) * K + koff + g * 8;
            u16* lb = sA + (size_t)(s * 256 + (tid & ~63)) * 8;
            __builtin_amdgcn_global_load_lds(as_g(ga), as_l(lb), 16, 0, 0);
        }
#pragma unroll
        for (int s = 0; s < 8; ++s) {
            int p = s * 256 + tid;
            int r = p >> 3, c = p & 7;
            int g = c ^ (r & 7);
            const u16* ga = Wt + (size_t)r * KC + kk + g * 8;
            u16* lb = sB + (size_t)(s * 256 + (tid & ~63)) * 8;
            __builtin_amdgcn_global_load_lds(as_g(ga), as_l(lb), 16, 0, 0);
        }
        __syncthreads();
#pragma unroll
        for (int kk2 = 0; kk2 < 2; ++kk2) {
            s16x8 av[4], bv[4];
#pragma unroll
            for (int m = 0; m < 4; ++m) {
                int r = m * 16 + lr;
                int cidx = kk2 * 4 + lk;
                int off = r * 128 + ((cidx ^ (lr & 7)) << 4);
                av[m] = *reinterpret_cast<const s16x8*>(
                    reinterpret_cast<const char*>(sA) + off);
            }
#pragma unroll
            for (int n = 0; n < 4; ++n) {
                int r = w * 64 + n * 16 + lr;
                int cidx = kk2 * 4 + lk;
                int off = r * 128 + ((cidx ^ (lr & 7)) << 4);
                bv[n] = *reinterpret_cast<const s16x8*>(
                    reinterpret_cast<const char*>(sB) + off);
            }
#pragma unroll
            for (int m = 0; m < 4; ++m)
#pragma unroll
                for (int n = 0; n < 4; ++n)
                    acc[m][n] = __builtin_amdgcn_mfma_f32_16x16x32_bf16(
                        av[m], bv[n], acc[m][n], 0, 0, 0);
        }
        __syncthreads();
    }

    float bb[4];
#pragma unroll
    for (int n = 0; n < 4; ++n) bb[n] = bias[w * 64 + n * 16 + lr];
#pragma unroll
    for (int m = 0; m < 4; ++m) {
#pragma unroll
        for (int n = 0; n < 4; ++n) {
            int col = w * 64 + n * 16 + lr;
#pragma unroll
            for (int i = 0; i < 4; ++i) {
                int row = row0 + m * 16 + lk * 4 + i;
                size_t o = (size_t)row * 256 + col;
                float z = acc[m][n][i] + bb[n];
                if (MODE == 0) {
                    z = fmaxf(z, 0.f);
                    outb[o] = f2bf(z);
                } else {
                    if (row < NN) {
                        z = fmaxf(z, fmaxf(bf2f(h1b[o]), bf2f(h2b[o])));
                        outf[o] = z;
                    }
                }
            }
        }
    }
}

extern "C" void kernel_launch(void* const* d_in, const int* in_sizes, int n_in,
                              void* d_out, int out_size, void* d_ws, size_t ws_size,
                              hipStream_t stream) {
    const float* x   = (const float*)d_in[0];
    const int*   ei  = (const int*)d_in[1];
    const float* Wl0 = (const float*)d_in[2];
    const float* bl0 = (const float*)d_in[3];
    const float* Wr0 = (const float*)d_in[4];
    const float* Wl1 = (const float*)d_in[5];
    const float* bl1 = (const float*)d_in[6];
    const float* Wr1 = (const float*)d_in[7];
    const float* Wl2 = (const float*)d_in[8];
    const float* bl2 = (const float*)d_in[9];
    const float* Wr2 = (const float*)d_in[10];
    float* out = (float*)d_out;

    const int N = NN;
    const int E = in_sizes[1] / 2;
    const int* dst = ei;          // edge_index[0]
    const int* src = ei + E;      // edge_index[1]

    char* wsp = (char*)d_ws;
    size_t off = 0;
    auto carve = [&](size_t bytes) {
        char* p = wsp + off;
        off += (bytes + 255) & ~(size_t)255;
        return p;
    };
    int* deg    = (int*)carve((size_t)N * 4);
    int* rowptr = (int*)carve((size_t)(N + 1) * 4);
    int* fpos   = (int*)carve((size_t)N * 4);
    int* bsum   = (int*)carve(64 * 4);
    int* colb   = (int*)carve((size_t)E * 4);
    u16* xb     = (u16*)carve((size_t)MPAD * 128 * 2);
    u16* aggb   = (u16*)carve((size_t)MPAD * 256 * 2);
    u16* h1b    = (u16*)carve((size_t)MPAD * 256 * 2);
    u16* h2b    = (u16*)carve((size_t)MPAD * 256 * 2);
    u16* Wt0    = (u16*)carve((size_t)256 * 256 * 2);
    u16* Wt1    = (u16*)carve((size_t)256 * 512 * 2);
    u16* Wt2    = (u16*)carve((size_t)256 * 512 * 2);
    (void)ws_size; (void)n_in; (void)out_size;

    hipMemsetAsync(deg, 0, (size_t)N * 4, stream);
    hipMemsetAsync(fpos, 0, (size_t)N * 4, stream);

    k_count<<<(E + 255) / 256, 256, 0, stream>>>(dst, E, deg);
    int nb = (N + 1023) / 1024;   // 49
    k_scan1<<<nb, 256, 0, stream>>>(deg, N, rowptr, bsum);
    k_scan2<<<1, 64, 0, stream>>>(bsum, nb);
    k_scan3<<<(N + 255) / 256, 256, 0, stream>>>(rowptr, bsum, N, E);
    k_fill<<<(E + 255) / 256, 256, 0, stream>>>(dst, src, E, rowptr, fpos, colb);

    // casts
    k_castx<<<(MPAD * 128 / 4) / 256, 256, 0, stream>>>(x, xb);
    k_wcat<<<256, 256, 0, stream>>>(Wl0, Wr0, 128, Wt0);
    k_wcat<<<512, 256, 0, stream>>>(Wl1, Wr1, 256, Wt1);
    k_wcat<<<512, 256, 0, stream>>>(Wl2, Wr2, 256, Wt2);

    const int GB = MPAD / 64;   // 782 blocks
    const int GA = MPAD / 4;    // 12512 blocks

    // layer 0: K=128
    k_aggb<128><<<GA, 256, 0, stream>>>(xb, rowptr, colb, aggb);
    k_mgemm<128, 0><<<GB, 256, 0, stream>>>(aggb, xb, Wt0, bl0, nullptr, nullptr,
                                            h1b, nullptr);
    // layer 1: K=256
    k_aggb<256><<<GA, 256, 0, stream>>>(h1b, rowptr, colb, aggb);
    k_mgemm<256, 0><<<GB, 256, 0, stream>>>(aggb, h1b, Wt1, bl1, nullptr, nullptr,
                                            h2b, nullptr);
    // layer 2: K=256, JK-max epilogue
    k_aggb<256><<<GA, 256, 0, stream>>>(h2b, rowptr, colb, aggb);
    k_mgemm<256, 1><<<GB, 256, 0, stream>>>(aggb, h2b, Wt2, bl2, h1b, h2b,
                                            nullptr, out);
}